// Round 1
// baseline (865.397 us; speedup 1.0000x reference)
//
#include <hip/hip_runtime.h>

#define N_ATOMS   50000
#define ATOM_FDIM 133
#define HIDDEN    128
#define DEPTH     3
#define N_EDGES   800000
#define N_MOLS    1024
#define BN_EPS    1e-5f

// ---------------- histogram ----------------
__global__ void hist_kernel(const int* __restrict__ idx, int n, int* __restrict__ cnt) {
    int i = blockIdx.x * blockDim.x + threadIdx.x;
    if (i < n) atomicAdd(&cnt[idx[i]], 1);
}

// ---------------- hierarchical exclusive scan (for CSR rowptr) ----------------
__global__ void scan_block_kernel(const int* __restrict__ in, int* __restrict__ out,
                                  int* __restrict__ bsum, int n) {
    __shared__ int buf[256];
    int i = blockIdx.x * 256 + threadIdx.x;
    int v = (i < n) ? in[i] : 0;
    buf[threadIdx.x] = v;
    __syncthreads();
    #pragma unroll
    for (int off = 1; off < 256; off <<= 1) {
        int t = (threadIdx.x >= off) ? buf[threadIdx.x - off] : 0;
        __syncthreads();
        buf[threadIdx.x] += t;
        __syncthreads();
    }
    if (i < n) out[i] = buf[threadIdx.x] - v;   // exclusive within block
    if (threadIdx.x == 255) bsum[blockIdx.x] = buf[255];
}

__global__ void scan_top_kernel(int* __restrict__ bsum, int nb) {
    __shared__ int buf[256];
    int v = (threadIdx.x < nb) ? bsum[threadIdx.x] : 0;
    buf[threadIdx.x] = v;
    __syncthreads();
    #pragma unroll
    for (int off = 1; off < 256; off <<= 1) {
        int t = (threadIdx.x >= off) ? buf[threadIdx.x - off] : 0;
        __syncthreads();
        buf[threadIdx.x] += t;
        __syncthreads();
    }
    if (threadIdx.x < nb) bsum[threadIdx.x] = buf[threadIdx.x] - v;  // exclusive
}

__global__ void scan_add_kernel(const int* __restrict__ partial, const int* __restrict__ bsum,
                                int* __restrict__ rowptr, int* __restrict__ wcur,
                                int n, int total) {
    int i = blockIdx.x * 256 + threadIdx.x;
    if (i < n) {
        int v = partial[i] + bsum[blockIdx.x];
        rowptr[i] = v;
        wcur[i]   = v;
    }
    if (i == 0) rowptr[n] = total;
}

// ---------------- CSR fill ----------------
__global__ void fill_csr_kernel(const int* __restrict__ src, const int* __restrict__ tgt,
                                int n, int* __restrict__ wcur, int* __restrict__ col) {
    int e = blockIdx.x * blockDim.x + threadIdx.x;
    if (e < n) {
        int t = tgt[e];
        int p = atomicAdd(&wcur[t], 1);
        col[p] = src[e];
    }
}

// ---------------- mol offsets via binary search (segment_ids sorted) ----------------
__global__ void mol_offsets_kernel(const int* __restrict__ seg, int* __restrict__ off) {
    int m = blockIdx.x * blockDim.x + threadIdx.x;
    if (m > N_MOLS) return;
    int lo = 0, hi = N_ATOMS;
    while (lo < hi) {
        int mid = (lo + hi) >> 1;
        if (seg[mid] < m) lo = mid + 1; else hi = mid;
    }
    off[m] = lo;
}

// ---------------- GEMM: C = act(A[M,K] @ W[K,128] + b), optional column stats ----------------
#define GM_BM 64
#define GM_BK 32
#define AS_STRIDE 68   // padded: float4-aligned, 4-way store conflict only

template<bool RELU, bool STATS>
__global__ __launch_bounds__(256) void gemm_kernel(
    const float* __restrict__ A, const float* __restrict__ W,
    const float* __restrict__ bias, float* __restrict__ C,
    int M, int K, float* __restrict__ s1, float* __restrict__ s2)
{
    __shared__ __align__(16) float As[GM_BK * AS_STRIDE];  // As[kk*68 + r]
    __shared__ __align__(16) float Ws[GM_BK * 128];        // Ws[kk*128 + c]

    int t = threadIdx.x;
    int row0 = blockIdx.x * GM_BM;
    int tx = t & 31, ty = t >> 5;
    int c0 = tx * 4, r0 = ty * 8;

    float acc[8][4];
    #pragma unroll
    for (int j = 0; j < 8; ++j)
        #pragma unroll
        for (int i = 0; i < 4; ++i) acc[j][i] = 0.f;

    int a_kk = t & 31, a_rb = (t >> 5) * 8;
    int w_c = t & 127, w_kb = (t >> 7) * 16;

    for (int k0 = 0; k0 < K; k0 += GM_BK) {
        #pragma unroll
        for (int i = 0; i < 8; ++i) {
            int r = a_rb + i;
            int row = row0 + r, k = k0 + a_kk;
            float v = (row < M && k < K) ? A[row * K + k] : 0.f;
            As[a_kk * AS_STRIDE + r] = v;
        }
        #pragma unroll
        for (int i = 0; i < 16; ++i) {
            int kk = w_kb + i;
            int k = k0 + kk;
            float v = (k < K) ? W[k * 128 + w_c] : 0.f;
            Ws[kk * 128 + w_c] = v;
        }
        __syncthreads();
        #pragma unroll 4
        for (int kk = 0; kk < GM_BK; ++kk) {
            float4 w4  = *(const float4*)&Ws[kk * 128 + c0];
            float4 a40 = *(const float4*)&As[kk * AS_STRIDE + r0];
            float4 a41 = *(const float4*)&As[kk * AS_STRIDE + r0 + 4];
            float a[8] = {a40.x, a40.y, a40.z, a40.w, a41.x, a41.y, a41.z, a41.w};
            #pragma unroll
            for (int j = 0; j < 8; ++j) {
                acc[j][0] += a[j] * w4.x;
                acc[j][1] += a[j] * w4.y;
                acc[j][2] += a[j] * w4.z;
                acc[j][3] += a[j] * w4.w;
            }
        }
        __syncthreads();
    }

    float bx = bias[c0], by = bias[c0 + 1], bz = bias[c0 + 2], bw = bias[c0 + 3];
    float ps[4] = {0, 0, 0, 0}, pss[4] = {0, 0, 0, 0};
    #pragma unroll
    for (int j = 0; j < 8; ++j) {
        int row = row0 + r0 + j;
        if (row < M) {
            float4 o;
            o.x = acc[j][0] + bx;
            o.y = acc[j][1] + by;
            o.z = acc[j][2] + bz;
            o.w = acc[j][3] + bw;
            if (STATS) {
                ps[0] += o.x;  pss[0] += o.x * o.x;
                ps[1] += o.y;  pss[1] += o.y * o.y;
                ps[2] += o.z;  pss[2] += o.z * o.z;
                ps[3] += o.w;  pss[3] += o.w * o.w;
            }
            if (RELU) {
                o.x = fmaxf(o.x, 0.f); o.y = fmaxf(o.y, 0.f);
                o.z = fmaxf(o.z, 0.f); o.w = fmaxf(o.w, 0.f);
            }
            *(float4*)&C[row * 128 + c0] = o;
        }
    }

    if (STATS) {
        __syncthreads();
        float* red1 = Ws;          // 8*128 floats
        float* red2 = Ws + 1024;   // 8*128 floats
        #pragma unroll
        for (int i = 0; i < 4; ++i) {
            red1[ty * 128 + c0 + i] = ps[i];
            red2[ty * 128 + c0 + i] = pss[i];
        }
        __syncthreads();
        if (t < 128) {
            float s = 0.f, q = 0.f;
            #pragma unroll
            for (int g = 0; g < 8; ++g) {
                s += red1[g * 128 + t];
                q += red2[g * 128 + t];
            }
            atomicAdd(&s1[t], s);
            atomicAdd(&s2[t], q);
        }
    }
}

// ---------------- aggregate: agg[i] = (1+eps)*x[i] + sum_{j in CSR(i)} x[j] ----------------
__global__ __launch_bounds__(256) void aggregate_kernel(
    const float* __restrict__ x, const int* __restrict__ rowptr,
    const int* __restrict__ col, const float* __restrict__ eps_param, int d,
    float* __restrict__ agg)
{
    int gw = (blockIdx.x * 256 + threadIdx.x) >> 6;   // one wave per atom
    int lane = threadIdx.x & 63;
    if (gw >= N_ATOMS) return;
    float e1 = 1.0f + eps_param[d];
    const float2* x2 = (const float2*)x;
    float2 a = x2[gw * 64 + lane];
    float2 acc;
    acc.x = a.x * e1;
    acc.y = a.y * e1;
    int s = rowptr[gw], e = rowptr[gw + 1];
    for (int i = s; i < e; ++i) {
        int sc = col[i];
        float2 v = x2[sc * 64 + lane];
        acc.x += v.x;
        acc.y += v.y;
    }
    ((float2*)agg)[gw * 64 + lane] = acc;
}

// ---------------- BN finalize: scale/shift per channel ----------------
__global__ void bn_finalize_kernel(const float* __restrict__ s1, const float* __restrict__ s2,
                                   const float* __restrict__ gamma, const float* __restrict__ beta,
                                   int d, float* __restrict__ scale, float* __restrict__ shift)
{
    int c = threadIdx.x;
    float inv_n = 1.0f / (float)N_ATOMS;
    float mean = s1[c] * inv_n;
    float var = s2[c] * inv_n - mean * mean;
    var = fmaxf(var, 0.f);
    float sc = gamma[d * 128 + c] * rsqrtf(var + BN_EPS);
    scale[c] = sc;
    shift[c] = beta[d * 128 + c] - mean * sc;
}

// ---------------- BN apply + ReLU ----------------
__global__ void bn_apply_relu_kernel(const float* __restrict__ h, const float* __restrict__ scale,
                                     const float* __restrict__ shift, float* __restrict__ x)
{
    int i = blockIdx.x * blockDim.x + threadIdx.x;   // float4 index
    const int n4 = N_ATOMS * 128 / 4;
    if (i >= n4) return;
    int c4 = (i & 31) * 4;
    float4 v = ((const float4*)h)[i];
    float4 o;
    o.x = fmaxf(v.x * scale[c4]     + shift[c4],     0.f);
    o.y = fmaxf(v.y * scale[c4 + 1] + shift[c4 + 1], 0.f);
    o.z = fmaxf(v.z * scale[c4 + 2] + shift[c4 + 2], 0.f);
    o.w = fmaxf(v.w * scale[c4 + 3] + shift[c4 + 3], 0.f);
    ((float4*)x)[i] = o;
}

// ---------------- per-molecule mean pooling ----------------
__global__ void pool_kernel(const float* __restrict__ x, const int* __restrict__ off,
                            float* __restrict__ out)
{
    int m = blockIdx.x;
    int c = threadIdx.x;     // 128 threads
    int s = off[m], e = off[m + 1];
    float acc = 0.f;
    for (int r = s; r < e; ++r) acc += x[r * 128 + c];
    int cnt = e - s;
    out[m * 128 + c] = (cnt > 0) ? acc / (float)cnt : 0.f;
}

// ---------------- launcher ----------------
extern "C" void kernel_launch(void* const* d_in, const int* in_sizes, int n_in,
                              void* d_out, int out_size, void* d_ws, size_t ws_size,
                              hipStream_t stream)
{
    const float* f_atoms   = (const float*)d_in[0];
    const float* W_in      = (const float*)d_in[1];
    const float* b_in      = (const float*)d_in[2];
    const float* W1        = (const float*)d_in[3];
    const float* b1        = (const float*)d_in[4];
    const float* W2        = (const float*)d_in[5];
    const float* b2        = (const float*)d_in[6];
    const float* gamma     = (const float*)d_in[7];
    const float* beta      = (const float*)d_in[8];
    const float* eps_param = (const float*)d_in[9];
    const int*   edge_index= (const int*)d_in[10];
    const int*   seg       = (const int*)d_in[11];
    const int*   src = edge_index;
    const int*   tgt = edge_index + N_EDGES;
    float* out = (float*)d_out;

    char* ws = (char*)d_ws;
    size_t off = 0;
    auto alloc = [&](size_t bytes) -> char* {
        char* p = ws + off;
        off += (bytes + 255) & ~(size_t)255;
        return p;
    };
    float* x      = (float*)alloc((size_t)N_ATOMS * HIDDEN * 4);
    float* bufA   = (float*)alloc((size_t)N_ATOMS * HIDDEN * 4);
    float* bufB   = (float*)alloc((size_t)N_ATOMS * HIDDEN * 4);
    int*   rowptr = (int*)alloc((N_ATOMS + 1) * 4);
    int*   wcur   = (int*)alloc(N_ATOMS * 4);
    int*   partial= (int*)alloc(N_ATOMS * 4);
    int*   bsum   = (int*)alloc(256 * 4);
    int*   col    = (int*)alloc((size_t)N_EDGES * 4);
    float* s1     = (float*)alloc(128 * 4);
    float* s2     = (float*)alloc(128 * 4);
    float* scale  = (float*)alloc(128 * 4);
    float* shiftb = (float*)alloc(128 * 4);
    int*   moloff = (int*)alloc((N_MOLS + 1) * 4);

    // ---- CSR build (reused across all 3 depths) ----
    hipMemsetAsync(wcur, 0, N_ATOMS * 4, stream);
    hist_kernel<<<(N_EDGES + 255) / 256, 256, 0, stream>>>(tgt, N_EDGES, wcur);
    const int NB = (N_ATOMS + 255) / 256;  // 196 <= 256
    scan_block_kernel<<<NB, 256, 0, stream>>>(wcur, partial, bsum, N_ATOMS);
    scan_top_kernel<<<1, 256, 0, stream>>>(bsum, NB);
    scan_add_kernel<<<NB, 256, 0, stream>>>(partial, bsum, rowptr, wcur, N_ATOMS, N_EDGES);
    fill_csr_kernel<<<(N_EDGES + 255) / 256, 256, 0, stream>>>(src, tgt, N_EDGES, wcur, col);

    // ---- mol offsets ----
    mol_offsets_kernel<<<(N_MOLS + 1 + 255) / 256, 256, 0, stream>>>(seg, moloff);

    // ---- input projection + ReLU ----
    const int GB = (N_ATOMS + GM_BM - 1) / GM_BM;  // 782
    gemm_kernel<true, false><<<GB, 256, 0, stream>>>(f_atoms, W_in, b_in, x,
                                                     N_ATOMS, ATOM_FDIM, nullptr, nullptr);

    for (int d = 0; d < DEPTH; ++d) {
        aggregate_kernel<<<N_ATOMS / 4, 256, 0, stream>>>(x, rowptr, col, eps_param, d, bufA);
        gemm_kernel<true, false><<<GB, 256, 0, stream>>>(bufA, W1 + d * HIDDEN * HIDDEN,
                                                         b1 + d * HIDDEN, bufB,
                                                         N_ATOMS, HIDDEN, nullptr, nullptr);
        hipMemsetAsync(s1, 0, 128 * 4, stream);
        hipMemsetAsync(s2, 0, 128 * 4, stream);
        gemm_kernel<false, true><<<GB, 256, 0, stream>>>(bufB, W2 + d * HIDDEN * HIDDEN,
                                                         b2 + d * HIDDEN, bufA,
                                                         N_ATOMS, HIDDEN, s1, s2);
        bn_finalize_kernel<<<1, 128, 0, stream>>>(s1, s2, gamma, beta, d, scale, shiftb);
        bn_apply_relu_kernel<<<(N_ATOMS * 128 / 4 + 255) / 256, 256, 0, stream>>>(bufA, scale, shiftb, x);
    }

    pool_kernel<<<N_MOLS, 128, 0, stream>>>(x, moloff, out);
}

// Round 2
// 647.583 us; speedup vs baseline: 1.3363x; 1.3363x over previous
//
#include <hip/hip_runtime.h>
#include <hip/hip_fp16.h>

#define N_ATOMS   50000
#define ATOM_FDIM 133
#define HIDDEN    128
#define DEPTH     3
#define N_EDGES   800000
#define N_MOLS    1024
#define BN_EPS    1e-5f

struct __align__(8) half4pack { __half2 a, b; };

// ---------------- histogram ----------------
__global__ void hist_kernel(const int* __restrict__ idx, int n, int* __restrict__ cnt) {
    int i = blockIdx.x * blockDim.x + threadIdx.x;
    if (i < n) atomicAdd(&cnt[idx[i]], 1);
}

// ---------------- hierarchical exclusive scan (for CSR rowptr) ----------------
__global__ void scan_block_kernel(const int* __restrict__ in, int* __restrict__ out,
                                  int* __restrict__ bsum, int n) {
    __shared__ int buf[256];
    int i = blockIdx.x * 256 + threadIdx.x;
    int v = (i < n) ? in[i] : 0;
    buf[threadIdx.x] = v;
    __syncthreads();
    #pragma unroll
    for (int off = 1; off < 256; off <<= 1) {
        int t = (threadIdx.x >= off) ? buf[threadIdx.x - off] : 0;
        __syncthreads();
        buf[threadIdx.x] += t;
        __syncthreads();
    }
    if (i < n) out[i] = buf[threadIdx.x] - v;
    if (threadIdx.x == 255) bsum[blockIdx.x] = buf[255];
}

__global__ void scan_top_kernel(int* __restrict__ bsum, int nb) {
    __shared__ int buf[256];
    int v = (threadIdx.x < nb) ? bsum[threadIdx.x] : 0;
    buf[threadIdx.x] = v;
    __syncthreads();
    #pragma unroll
    for (int off = 1; off < 256; off <<= 1) {
        int t = (threadIdx.x >= off) ? buf[threadIdx.x - off] : 0;
        __syncthreads();
        buf[threadIdx.x] += t;
        __syncthreads();
    }
    if (threadIdx.x < nb) bsum[threadIdx.x] = buf[threadIdx.x] - v;
}

__global__ void scan_add_kernel(const int* __restrict__ partial, const int* __restrict__ bsum,
                                int* __restrict__ rowptr, int* __restrict__ wcur,
                                int n, int total) {
    int i = blockIdx.x * 256 + threadIdx.x;
    if (i < n) {
        int v = partial[i] + bsum[blockIdx.x];
        rowptr[i] = v;
        wcur[i]   = v;
    }
    if (i == 0) rowptr[n] = total;
}

// ---------------- CSR fill ----------------
__global__ void fill_csr_kernel(const int* __restrict__ src, const int* __restrict__ tgt,
                                int n, int* __restrict__ wcur, int* __restrict__ col) {
    int e = blockIdx.x * blockDim.x + threadIdx.x;
    if (e < n) {
        int t = tgt[e];
        int p = atomicAdd(&wcur[t], 1);
        col[p] = src[e];
    }
}

// ---------------- mol offsets (binary search; seg sorted) + zero BN stats ----------------
__global__ void mol_offsets_zero_kernel(const int* __restrict__ seg, int* __restrict__ off,
                                        float* __restrict__ stats /* 768 floats */) {
    int m = blockIdx.x * blockDim.x + threadIdx.x;
    if (m < 768) stats[m] = 0.f;
    if (m > N_MOLS) return;
    int lo = 0, hi = N_ATOMS;
    while (lo < hi) {
        int mid = (lo + hi) >> 1;
        if (seg[mid] < m) lo = mid + 1; else hi = mid;
    }
    off[m] = lo;
}

// ---------------- GEMM: 128x128 tile, 256 threads, 8x8 acc/thread ----------------
// C = act(A[M,K] @ W[K,128] + b). OUTH: write fp16 to Ch instead of fp32 C.
// STATS: accumulate per-channel sum / sumsq (pre-activation) into s1/s2.
#define AS_S 132   // padded LDS stride for As[kk][row]

template<bool RELU, bool STATS, bool OUTH, bool K4>
__global__ __launch_bounds__(256, 4) void gemm128(
    const float* __restrict__ A, const float* __restrict__ W,
    const float* __restrict__ bias, float* __restrict__ C, __half* __restrict__ Ch,
    int M, int K, float* __restrict__ s1, float* __restrict__ s2)
{
    __shared__ __align__(16) float As[32 * AS_S];   // [kk][row] transposed A tile
    __shared__ __align__(16) float Ws[32 * 128];    // [kk][col]

    const int t = threadIdx.x;
    const int row0 = blockIdx.x * 128;
    const int tx = t & 15, ty = t >> 4;
    const int cA = tx * 4, cB = 64 + tx * 4;
    const int r0 = ty * 8;

    float acc[8][8];
    #pragma unroll
    for (int j = 0; j < 8; ++j)
        #pragma unroll
        for (int i = 0; i < 8; ++i) acc[j][i] = 0.f;

    for (int k0 = 0; k0 < K; k0 += 32) {
        // ---- stage A (transpose into As[kk][row]) ----
        if (K4) {
            const int kq = t & 7, rb = t >> 3;      // kq: float4 chunk, rb: 0..31
            #pragma unroll
            for (int i = 0; i < 4; ++i) {
                int r = rb + 32 * i;
                int row = row0 + r;
                float4 v = make_float4(0.f, 0.f, 0.f, 0.f);
                if (row < M) v = *(const float4*)&A[(size_t)row * K + k0 + kq * 4];
                As[(kq * 4 + 0) * AS_S + r] = v.x;
                As[(kq * 4 + 1) * AS_S + r] = v.y;
                As[(kq * 4 + 2) * AS_S + r] = v.z;
                As[(kq * 4 + 3) * AS_S + r] = v.w;
            }
        } else {
            const int kk2 = t & 31, rb2 = t >> 5;   // rb2: 0..7
            int k = k0 + kk2;
            #pragma unroll
            for (int i = 0; i < 16; ++i) {
                int r = rb2 + 8 * i;
                int row = row0 + r;
                float v = (row < M && k < K) ? A[(size_t)row * K + k] : 0.f;
                As[kk2 * AS_S + r] = v;
            }
        }
        // ---- stage W ----
        {
            const int c4 = (t & 31) * 4, kr = t >> 5;
            #pragma unroll
            for (int i = 0; i < 4; ++i) {
                int kk = kr + 8 * i;
                int k = k0 + kk;
                float4 v = make_float4(0.f, 0.f, 0.f, 0.f);
                if (k < K) v = *(const float4*)&W[(size_t)k * 128 + c4];
                *(float4*)&Ws[kk * 128 + c4] = v;
            }
        }
        __syncthreads();
        // ---- compute ----
        #pragma unroll 8
        for (int kk = 0; kk < 32; ++kk) {
            float4 a0 = *(const float4*)&As[kk * AS_S + r0];
            float4 a1 = *(const float4*)&As[kk * AS_S + r0 + 4];
            float4 w0 = *(const float4*)&Ws[kk * 128 + cA];
            float4 w1 = *(const float4*)&Ws[kk * 128 + cB];
            float ar[8] = {a0.x, a0.y, a0.z, a0.w, a1.x, a1.y, a1.z, a1.w};
            #pragma unroll
            for (int j = 0; j < 8; ++j) {
                acc[j][0] += ar[j] * w0.x;
                acc[j][1] += ar[j] * w0.y;
                acc[j][2] += ar[j] * w0.z;
                acc[j][3] += ar[j] * w0.w;
                acc[j][4] += ar[j] * w1.x;
                acc[j][5] += ar[j] * w1.y;
                acc[j][6] += ar[j] * w1.z;
                acc[j][7] += ar[j] * w1.w;
            }
        }
        __syncthreads();
    }

    float4 bA = *(const float4*)&bias[cA];
    float4 bB = *(const float4*)&bias[cB];
    float ps[8], pss[8];
    #pragma unroll
    for (int i = 0; i < 8; ++i) { ps[i] = 0.f; pss[i] = 0.f; }

    #pragma unroll
    for (int j = 0; j < 8; ++j) {
        int row = row0 + r0 + j;
        if (row < M) {
            float o[8];
            o[0] = acc[j][0] + bA.x; o[1] = acc[j][1] + bA.y;
            o[2] = acc[j][2] + bA.z; o[3] = acc[j][3] + bA.w;
            o[4] = acc[j][4] + bB.x; o[5] = acc[j][5] + bB.y;
            o[6] = acc[j][6] + bB.z; o[7] = acc[j][7] + bB.w;
            if (STATS) {
                #pragma unroll
                for (int i = 0; i < 8; ++i) { ps[i] += o[i]; pss[i] += o[i] * o[i]; }
            }
            if (RELU) {
                #pragma unroll
                for (int i = 0; i < 8; ++i) o[i] = fmaxf(o[i], 0.f);
            }
            if (OUTH) {
                half4pack p0, p1;
                p0.a = __float22half2_rn(make_float2(o[0], o[1]));
                p0.b = __float22half2_rn(make_float2(o[2], o[3]));
                p1.a = __float22half2_rn(make_float2(o[4], o[5]));
                p1.b = __float22half2_rn(make_float2(o[6], o[7]));
                *(half4pack*)&Ch[(size_t)row * 128 + cA] = p0;
                *(half4pack*)&Ch[(size_t)row * 128 + cB] = p1;
            } else {
                *(float4*)&C[(size_t)row * 128 + cA] = make_float4(o[0], o[1], o[2], o[3]);
                *(float4*)&C[(size_t)row * 128 + cB] = make_float4(o[4], o[5], o[6], o[7]);
            }
        }
    }

    if (STATS) {
        __syncthreads();
        float* red1 = As;             // need 16*128 = 2048 floats (As has 4224)
        float* red2 = Ws;             // 2048 of 4096
        #pragma unroll
        for (int i = 0; i < 4; ++i) {
            red1[ty * 128 + cA + i] = ps[i];
            red1[ty * 128 + cB + i] = ps[4 + i];
            red2[ty * 128 + cA + i] = pss[i];
            red2[ty * 128 + cB + i] = pss[4 + i];
        }
        __syncthreads();
        if (t < 128) {
            float s = 0.f, q = 0.f;
            #pragma unroll
            for (int g = 0; g < 16; ++g) {
                s += red1[g * 128 + t];
                q += red2[g * 128 + t];
            }
            atomicAdd(&s1[t], s);
            atomicAdd(&s2[t], q);
        }
    }
}

// ---------------- aggregate: agg[i] = (1+eps)*x[i] + sum_{j in CSR(i)} x[j] ----------------
// x stored fp16 (half2 per lane); accumulate fp32; 4-deep gather unroll for MLP.
__global__ __launch_bounds__(256) void aggregate_kernel(
    const __half2* __restrict__ xh2, const int* __restrict__ rowptr,
    const int* __restrict__ col, const float* __restrict__ eps_param, int d,
    float* __restrict__ agg)
{
    int gw = (blockIdx.x * 256 + threadIdx.x) >> 6;   // one wave per atom
    int lane = threadIdx.x & 63;
    float e1 = 1.0f + eps_param[d];
    float2 a = __half22float2(xh2[(size_t)gw * 64 + lane]);
    float2 acc;
    acc.x = a.x * e1;
    acc.y = a.y * e1;
    int s = rowptr[gw], e = rowptr[gw + 1];
    int i = s;
    for (; i + 4 <= e; i += 4) {
        int c0 = col[i], c1 = col[i + 1], c2 = col[i + 2], c3 = col[i + 3];
        __half2 v0 = xh2[(size_t)c0 * 64 + lane];
        __half2 v1 = xh2[(size_t)c1 * 64 + lane];
        __half2 v2 = xh2[(size_t)c2 * 64 + lane];
        __half2 v3 = xh2[(size_t)c3 * 64 + lane];
        float2 f0 = __half22float2(v0), f1 = __half22float2(v1);
        float2 f2 = __half22float2(v2), f3 = __half22float2(v3);
        acc.x += (f0.x + f1.x) + (f2.x + f3.x);
        acc.y += (f0.y + f1.y) + (f2.y + f3.y);
    }
    for (; i < e; ++i) {
        float2 f = __half22float2(xh2[(size_t)col[i] * 64 + lane]);
        acc.x += f.x;
        acc.y += f.y;
    }
    ((float2*)agg)[(size_t)gw * 64 + lane] = acc;
}

// ---------------- BN (stats -> scale/shift inline) + ReLU -> fp16 x ----------------
__global__ void bn_apply_relu_kernel(const float* __restrict__ h,
                                     const float* __restrict__ s1, const float* __restrict__ s2,
                                     const float* __restrict__ gamma, const float* __restrict__ beta,
                                     int d, __half* __restrict__ xh)
{
    int i = blockIdx.x * blockDim.x + threadIdx.x;   // float4 index
    const int n4 = N_ATOMS * 128 / 4;
    if (i >= n4) return;
    int c4 = (i & 31) * 4;
    const float inv_n = 1.0f / (float)N_ATOMS;
    float4 v = ((const float4*)h)[i];
    float o[4];
    float vv[4] = {v.x, v.y, v.z, v.w};
    #pragma unroll
    for (int u = 0; u < 4; ++u) {
        int c = c4 + u;
        float mean = s1[c] * inv_n;
        float var = fmaxf(s2[c] * inv_n - mean * mean, 0.f);
        float sc = gamma[d * 128 + c] * rsqrtf(var + BN_EPS);
        float sh = beta[d * 128 + c] - mean * sc;
        o[u] = fmaxf(vv[u] * sc + sh, 0.f);
    }
    half4pack p;
    p.a = __float22half2_rn(make_float2(o[0], o[1]));
    p.b = __float22half2_rn(make_float2(o[2], o[3]));
    *(half4pack*)&xh[(size_t)i * 4] = p;
}

// ---------------- per-molecule mean pooling (reads fp16 x) ----------------
__global__ void pool_kernel(const __half* __restrict__ xh, const int* __restrict__ off,
                            float* __restrict__ out)
{
    int m = blockIdx.x;
    int c = threadIdx.x;     // 128 threads
    int s = off[m], e = off[m + 1];
    float acc = 0.f;
    for (int r = s; r < e; ++r) acc += __half2float(xh[(size_t)r * 128 + c]);
    int cnt = e - s;
    out[m * 128 + c] = (cnt > 0) ? acc / (float)cnt : 0.f;
}

// ---------------- launcher ----------------
extern "C" void kernel_launch(void* const* d_in, const int* in_sizes, int n_in,
                              void* d_out, int out_size, void* d_ws, size_t ws_size,
                              hipStream_t stream)
{
    const float* f_atoms   = (const float*)d_in[0];
    const float* W_in      = (const float*)d_in[1];
    const float* b_in      = (const float*)d_in[2];
    const float* W1        = (const float*)d_in[3];
    const float* b1        = (const float*)d_in[4];
    const float* W2        = (const float*)d_in[5];
    const float* b2        = (const float*)d_in[6];
    const float* gamma     = (const float*)d_in[7];
    const float* beta      = (const float*)d_in[8];
    const float* eps_param = (const float*)d_in[9];
    const int*   edge_index= (const int*)d_in[10];
    const int*   seg       = (const int*)d_in[11];
    const int*   src = edge_index;
    const int*   tgt = edge_index + N_EDGES;
    float* out = (float*)d_out;

    char* ws = (char*)d_ws;
    size_t off = 0;
    auto alloc = [&](size_t bytes) -> char* {
        char* p = ws + off;
        off += (bytes + 255) & ~(size_t)255;
        return p;
    };
    __half* xh    = (__half*)alloc((size_t)N_ATOMS * HIDDEN * 2);
    float* bufA   = (float*)alloc((size_t)N_ATOMS * HIDDEN * 4);
    float* bufB   = (float*)alloc((size_t)N_ATOMS * HIDDEN * 4);
    int*   rowptr = (int*)alloc((N_ATOMS + 1) * 4);
    int*   wcur   = (int*)alloc(N_ATOMS * 4);
    int*   partial= (int*)alloc(N_ATOMS * 4);
    int*   bsum   = (int*)alloc(256 * 4);
    int*   col    = (int*)alloc((size_t)N_EDGES * 4);
    float* s12    = (float*)alloc(DEPTH * 256 * 4);   // [d][s1:128 | s2:128]
    int*   moloff = (int*)alloc((N_MOLS + 1) * 4);

    // ---- CSR build ----
    hipMemsetAsync(wcur, 0, N_ATOMS * 4, stream);
    hist_kernel<<<(N_EDGES + 255) / 256, 256, 0, stream>>>(tgt, N_EDGES, wcur);
    const int NB = (N_ATOMS + 255) / 256;
    scan_block_kernel<<<NB, 256, 0, stream>>>(wcur, partial, bsum, N_ATOMS);
    scan_top_kernel<<<1, 256, 0, stream>>>(bsum, NB);
    scan_add_kernel<<<NB, 256, 0, stream>>>(partial, bsum, rowptr, wcur, N_ATOMS, N_EDGES);
    fill_csr_kernel<<<(N_EDGES + 255) / 256, 256, 0, stream>>>(src, tgt, N_EDGES, wcur, col);

    // ---- mol offsets + zero BN stats ----
    mol_offsets_zero_kernel<<<5, 256, 0, stream>>>(seg, moloff, s12);

    // ---- input projection + ReLU -> fp16 x ----
    const int GB = (N_ATOMS + 127) / 128;   // 391
    gemm128<true, false, true, false><<<GB, 256, 0, stream>>>(
        f_atoms, W_in, b_in, nullptr, xh, N_ATOMS, ATOM_FDIM, nullptr, nullptr);

    for (int d = 0; d < DEPTH; ++d) {
        float* s1d = s12 + d * 256;
        float* s2d = s1d + 128;
        aggregate_kernel<<<N_ATOMS / 4, 256, 0, stream>>>(
            (const __half2*)xh, rowptr, col, eps_param, d, bufA);
        gemm128<true, false, false, true><<<GB, 256, 0, stream>>>(
            bufA, W1 + d * HIDDEN * HIDDEN, b1 + d * HIDDEN, bufB, nullptr,
            N_ATOMS, HIDDEN, nullptr, nullptr);
        gemm128<false, true, false, true><<<GB, 256, 0, stream>>>(
            bufB, W2 + d * HIDDEN * HIDDEN, b2 + d * HIDDEN, bufA, nullptr,
            N_ATOMS, HIDDEN, s1d, s2d);
        bn_apply_relu_kernel<<<(N_ATOMS * 128 / 4 + 255) / 256, 256, 0, stream>>>(
            bufA, s1d, s2d, gamma, beta, d, xh);
    }

    pool_kernel<<<N_MOLS, 128, 0, stream>>>(xh, moloff, out);
}

// Round 3
// 489.419 us; speedup vs baseline: 1.7682x; 1.3232x over previous
//
#include <hip/hip_runtime.h>
#include <hip/hip_fp16.h>

#define N_ATOMS   50000
#define ATOM_FDIM 133
#define HIDDEN    128
#define DEPTH     3
#define N_EDGES   800000
#define N_MOLS    1024
#define BN_EPS    1e-5f
#define K_IN_PAD  160   // 133 padded to 5*32

typedef _Float16 f16x8 __attribute__((ext_vector_type(8)));
typedef float    f32x4 __attribute__((ext_vector_type(4)));

struct __align__(8) half4pack { __half2 a, b; };

// ---------------- histogram ----------------
__global__ void hist_kernel(const int* __restrict__ idx, int n, int* __restrict__ cnt) {
    int i = blockIdx.x * blockDim.x + threadIdx.x;
    if (i < n) atomicAdd(&cnt[idx[i]], 1);
}

// ---------------- hierarchical exclusive scan ----------------
__global__ void scan_block_kernel(const int* __restrict__ in, int* __restrict__ out,
                                  int* __restrict__ bsum, int n) {
    __shared__ int buf[256];
    int i = blockIdx.x * 256 + threadIdx.x;
    int v = (i < n) ? in[i] : 0;
    buf[threadIdx.x] = v;
    __syncthreads();
    #pragma unroll
    for (int off = 1; off < 256; off <<= 1) {
        int t = (threadIdx.x >= off) ? buf[threadIdx.x - off] : 0;
        __syncthreads();
        buf[threadIdx.x] += t;
        __syncthreads();
    }
    if (i < n) out[i] = buf[threadIdx.x] - v;
    if (threadIdx.x == 255) bsum[blockIdx.x] = buf[255];
}

__global__ void scan_top_kernel(int* __restrict__ bsum, int nb) {
    __shared__ int buf[256];
    int v = (threadIdx.x < nb) ? bsum[threadIdx.x] : 0;
    buf[threadIdx.x] = v;
    __syncthreads();
    #pragma unroll
    for (int off = 1; off < 256; off <<= 1) {
        int t = (threadIdx.x >= off) ? buf[threadIdx.x - off] : 0;
        __syncthreads();
        buf[threadIdx.x] += t;
        __syncthreads();
    }
    if (threadIdx.x < nb) bsum[threadIdx.x] = buf[threadIdx.x] - v;
}

__global__ void scan_add_kernel(const int* __restrict__ partial, const int* __restrict__ bsum,
                                int* __restrict__ rowptr, int* __restrict__ wcur,
                                int n, int total) {
    int i = blockIdx.x * 256 + threadIdx.x;
    if (i < n) {
        int v = partial[i] + bsum[blockIdx.x];
        rowptr[i] = v;
        wcur[i]   = v;
    }
    if (i == 0) rowptr[n] = total;
}

// ---------------- CSR fill ----------------
__global__ void fill_csr_kernel(const int* __restrict__ src, const int* __restrict__ tgt,
                                int n, int* __restrict__ wcur, int* __restrict__ col) {
    int e = blockIdx.x * blockDim.x + threadIdx.x;
    if (e < n) {
        int t = tgt[e];
        int p = atomicAdd(&wcur[t], 1);
        col[p] = src[e];
    }
}

// ---------------- mol offsets + zero BN stats ----------------
__global__ void mol_offsets_zero_kernel(const int* __restrict__ seg, int* __restrict__ off,
                                        float* __restrict__ stats /* 768 floats */) {
    int m = blockIdx.x * blockDim.x + threadIdx.x;
    if (m < 768) stats[m] = 0.f;
    if (m > N_MOLS) return;
    int lo = 0, hi = N_ATOMS;
    while (lo < hi) {
        int mid = (lo + hi) >> 1;
        if (seg[mid] < m) lo = mid + 1; else hi = mid;
    }
    off[m] = lo;
}

// ---------------- convert f_atoms -> fp16, K padded 133->160 ----------------
__global__ void convert_atoms_kernel(const float* __restrict__ f, __half* __restrict__ Ah) {
    int i = blockIdx.x * 256 + threadIdx.x;   // one half4 chunk
    const int NCH = N_ATOMS * (K_IN_PAD / 4);
    if (i >= NCH) return;
    int row = i / (K_IN_PAD / 4);
    int c4  = (i - row * (K_IN_PAD / 4)) * 4;
    float v[4];
    #pragma unroll
    for (int u = 0; u < 4; ++u) {
        int k = c4 + u;
        v[u] = (k < ATOM_FDIM) ? f[(size_t)row * ATOM_FDIM + k] : 0.f;
    }
    half4pack p;
    p.a = __float22half2_rn(make_float2(v[0], v[1]));
    p.b = __float22half2_rn(make_float2(v[2], v[3]));
    *(half4pack*)&Ah[(size_t)row * K_IN_PAD + c4] = p;
}

// ---------------- convert + transpose weights to fp16 [n][k] ----------------
// layout in Wt: [0, 20480): Win_t (128 x 160 padded)
//               [20480, +3*16384): W1_t per depth
//               [69632, +3*16384): W2_t per depth
__global__ void convert_weights_kernel(const float* __restrict__ W_in,
                                       const float* __restrict__ W1,
                                       const float* __restrict__ W2,
                                       __half* __restrict__ Wt) {
    int i = blockIdx.x * 256 + threadIdx.x;
    const int TOT = 128 * K_IN_PAD + 2 * DEPTH * 128 * 128;
    if (i >= TOT) return;
    float v;
    if (i < 128 * K_IN_PAD) {
        int n = i / K_IN_PAD, k = i - n * K_IN_PAD;
        v = (k < ATOM_FDIM) ? W_in[(size_t)k * 128 + n] : 0.f;
    } else if (i < 128 * K_IN_PAD + DEPTH * 128 * 128) {
        int j = i - 128 * K_IN_PAD;
        int d = j >> 14, r = j & 16383;
        int n = r >> 7, k = r & 127;
        v = W1[((size_t)d * 128 + k) * 128 + n];
    } else {
        int j = i - 128 * K_IN_PAD - DEPTH * 128 * 128;
        int d = j >> 14, r = j & 16383;
        int n = r >> 7, k = r & 127;
        v = W2[((size_t)d * 128 + k) * 128 + n];
    }
    Wt[i] = __float2half(v);
}

// ---------------- MFMA fp16 GEMM: C[M,128] = act(A[M,K] @ Bt^T + bias) ----------------
// A fp16 [M][K], Bt fp16 [128][K] (Bt[n][k] = W[k][n]). 128x128 tile, 4 waves (2x2),
// each wave 64x64 via 4x4 grid of 16x16x32 MFMA. fp32 accumulate.
#define LDS_S 40   // padded stride (halves) for 32-half rows

template<bool RELU, bool STATS>
__global__ __launch_bounds__(256, 2) void mfma_gemm(
    const __half* __restrict__ A, const __half* __restrict__ Bt,
    const float* __restrict__ bias, __half* __restrict__ C,
    int M, int K, float* __restrict__ s1, float* __restrict__ s2)
{
    __shared__ __align__(16) __half As[128 * LDS_S];
    __shared__ __align__(16) __half Bs[128 * LDS_S];

    const int t = threadIdx.x;
    const int w = t >> 6, lane = t & 63;
    const int wm = w >> 1, wn = w & 1;
    const int l15 = lane & 15, quad = lane >> 4;
    const int row0 = blockIdx.x * 128;

    f32x4 acc[4][4];
    #pragma unroll
    for (int mt = 0; mt < 4; ++mt)
        #pragma unroll
        for (int nt = 0; nt < 4; ++nt) acc[mt][nt] = (f32x4){0.f, 0.f, 0.f, 0.f};

    for (int k0 = 0; k0 < K; k0 += 32) {
        // stage A tile: 128 rows x 32 halves = 512 x 16B chunks, 2 per thread
        #pragma unroll
        for (int i = 0; i < 2; ++i) {
            int c = t * 2 + i;
            int r = c >> 2, o = c & 3;
            int row = row0 + r;
            uint4 v = make_uint4(0, 0, 0, 0);
            if (row < M) v = *(const uint4*)&A[(size_t)row * K + k0 + o * 8];
            *(uint4*)&As[r * LDS_S + o * 8] = v;
        }
        // stage B tile: 128 n x 32 halves
        #pragma unroll
        for (int i = 0; i < 2; ++i) {
            int c = t * 2 + i;
            int r = c >> 2, o = c & 3;
            uint4 v = *(const uint4*)&Bt[(size_t)r * K + k0 + o * 8];
            *(uint4*)&Bs[r * LDS_S + o * 8] = v;
        }
        __syncthreads();

        f16x8 af[4], bf[4];
        #pragma unroll
        for (int mt = 0; mt < 4; ++mt)
            af[mt] = *(const f16x8*)&As[(wm * 64 + mt * 16 + l15) * LDS_S + quad * 8];
        #pragma unroll
        for (int nt = 0; nt < 4; ++nt)
            bf[nt] = *(const f16x8*)&Bs[(wn * 64 + nt * 16 + l15) * LDS_S + quad * 8];
        #pragma unroll
        for (int mt = 0; mt < 4; ++mt)
            #pragma unroll
            for (int nt = 0; nt < 4; ++nt)
                acc[mt][nt] = __builtin_amdgcn_mfma_f32_16x16x32_f16(af[mt], bf[nt], acc[mt][nt], 0, 0, 0);
        __syncthreads();
    }

    // epilogue: C/D layout col = lane&15, row = quad*4 + reg
    float ps[4] = {0, 0, 0, 0}, pss[4] = {0, 0, 0, 0};
    #pragma unroll
    for (int nt = 0; nt < 4; ++nt) {
        int col = wn * 64 + nt * 16 + l15;
        float b = bias[col];
        #pragma unroll
        for (int mt = 0; mt < 4; ++mt) {
            #pragma unroll
            for (int r = 0; r < 4; ++r) {
                int row = row0 + wm * 64 + mt * 16 + quad * 4 + r;
                if (row < M) {
                    float o = acc[mt][nt][r] + b;
                    if (STATS) { ps[nt] += o; pss[nt] += o * o; }
                    if (RELU) o = fmaxf(o, 0.f);
                    C[(size_t)row * 128 + col] = __float2half(o);
                }
            }
        }
    }

    if (STATS) {
        float* red1 = (float*)As;   // 8*128 floats = 4 KB (As is 10 KB)
        float* red2 = (float*)Bs;
        int contrib = wm * 4 + quad;          // 0..7
        __syncthreads();
        #pragma unroll
        for (int nt = 0; nt < 4; ++nt) {
            int col = wn * 64 + nt * 16 + l15;
            red1[contrib * 128 + col] = ps[nt];
            red2[contrib * 128 + col] = pss[nt];
        }
        __syncthreads();
        if (t < 128) {
            float s = 0.f, q = 0.f;
            #pragma unroll
            for (int g = 0; g < 8; ++g) {
                s += red1[g * 128 + t];
                q += red2[g * 128 + t];
            }
            atomicAdd(&s1[t], s);
            atomicAdd(&s2[t], q);
        }
    }
}

// ---------------- aggregate: fp16 in, fp16 out, fp32 accumulate ----------------
__global__ __launch_bounds__(256) void aggregate_kernel(
    const __half2* __restrict__ xh2, const int* __restrict__ rowptr,
    const int* __restrict__ col, const float* __restrict__ eps_param, int d,
    __half2* __restrict__ aggh2)
{
    int gw = (blockIdx.x * 256 + threadIdx.x) >> 6;   // one wave per atom
    int lane = threadIdx.x & 63;
    float e1 = 1.0f + eps_param[d];
    float2 a = __half22float2(xh2[(size_t)gw * 64 + lane]);
    float2 acc;
    acc.x = a.x * e1;
    acc.y = a.y * e1;
    int s = rowptr[gw], e = rowptr[gw + 1];
    int i = s;
    for (; i + 4 <= e; i += 4) {
        int c0 = col[i], c1 = col[i + 1], c2 = col[i + 2], c3 = col[i + 3];
        float2 f0 = __half22float2(xh2[(size_t)c0 * 64 + lane]);
        float2 f1 = __half22float2(xh2[(size_t)c1 * 64 + lane]);
        float2 f2 = __half22float2(xh2[(size_t)c2 * 64 + lane]);
        float2 f3 = __half22float2(xh2[(size_t)c3 * 64 + lane]);
        acc.x += (f0.x + f1.x) + (f2.x + f3.x);
        acc.y += (f0.y + f1.y) + (f2.y + f3.y);
    }
    for (; i < e; ++i) {
        float2 f = __half22float2(xh2[(size_t)col[i] * 64 + lane]);
        acc.x += f.x;
        acc.y += f.y;
    }
    aggh2[(size_t)gw * 64 + lane] = __float22half2_rn(acc);
}

// ---------------- BN (inline stats) + ReLU: fp16 h -> fp16 x ----------------
__global__ void bn_apply_relu_kernel(const __half* __restrict__ h,
                                     const float* __restrict__ s1, const float* __restrict__ s2,
                                     const float* __restrict__ gamma, const float* __restrict__ beta,
                                     int d, __half* __restrict__ xh)
{
    int i = blockIdx.x * blockDim.x + threadIdx.x;   // half4 chunk
    const int n4 = N_ATOMS * 128 / 4;
    if (i >= n4) return;
    int c4 = (i & 31) * 4;
    const float inv_n = 1.0f / (float)N_ATOMS;
    half4pack v = ((const half4pack*)h)[i];
    float2 f01 = __half22float2(v.a);
    float2 f23 = __half22float2(v.b);
    float vv[4] = {f01.x, f01.y, f23.x, f23.y};
    float o[4];
    #pragma unroll
    for (int u = 0; u < 4; ++u) {
        int c = c4 + u;
        float mean = s1[c] * inv_n;
        float var = fmaxf(s2[c] * inv_n - mean * mean, 0.f);
        float sc = gamma[d * 128 + c] * rsqrtf(var + BN_EPS);
        float sh = beta[d * 128 + c] - mean * sc;
        o[u] = fmaxf(vv[u] * sc + sh, 0.f);
    }
    half4pack p;
    p.a = __float22half2_rn(make_float2(o[0], o[1]));
    p.b = __float22half2_rn(make_float2(o[2], o[3]));
    *(half4pack*)&xh[(size_t)i * 4] = p;
}

// ---------------- per-molecule mean pooling ----------------
__global__ void pool_kernel(const __half* __restrict__ xh, const int* __restrict__ off,
                            float* __restrict__ out)
{
    int m = blockIdx.x;
    int c = threadIdx.x;     // 128 threads
    int s = off[m], e = off[m + 1];
    float acc = 0.f;
    for (int r = s; r < e; ++r) acc += __half2float(xh[(size_t)r * 128 + c]);
    int cnt = e - s;
    out[m * 128 + c] = (cnt > 0) ? acc / (float)cnt : 0.f;
}

// ---------------- launcher ----------------
extern "C" void kernel_launch(void* const* d_in, const int* in_sizes, int n_in,
                              void* d_out, int out_size, void* d_ws, size_t ws_size,
                              hipStream_t stream)
{
    const float* f_atoms   = (const float*)d_in[0];
    const float* W_in      = (const float*)d_in[1];
    const float* b_in      = (const float*)d_in[2];
    const float* W1        = (const float*)d_in[3];
    const float* b1        = (const float*)d_in[4];
    const float* W2        = (const float*)d_in[5];
    const float* b2        = (const float*)d_in[6];
    const float* gamma     = (const float*)d_in[7];
    const float* beta      = (const float*)d_in[8];
    const float* eps_param = (const float*)d_in[9];
    const int*   edge_index= (const int*)d_in[10];
    const int*   seg       = (const int*)d_in[11];
    const int*   src = edge_index;
    const int*   tgt = edge_index + N_EDGES;
    float* out = (float*)d_out;

    char* ws = (char*)d_ws;
    size_t off = 0;
    auto alloc = [&](size_t bytes) -> char* {
        char* p = ws + off;
        off += (bytes + 255) & ~(size_t)255;
        return p;
    };
    __half* xh    = (__half*)alloc((size_t)N_ATOMS * HIDDEN * 2);
    __half* aggh  = (__half*)alloc((size_t)N_ATOMS * HIDDEN * 2);  // also gemm2 out
    __half* hh    = (__half*)alloc((size_t)N_ATOMS * HIDDEN * 2);  // gemm1 out
    __half* Ah    = (__half*)alloc((size_t)N_ATOMS * K_IN_PAD * 2);
    __half* Wt    = (__half*)alloc((size_t)(128 * K_IN_PAD + 2 * DEPTH * 128 * 128) * 2);
    int*   rowptr = (int*)alloc((N_ATOMS + 1) * 4);
    int*   wcur   = (int*)alloc(N_ATOMS * 4);
    int*   partial= (int*)alloc(N_ATOMS * 4);
    int*   bsum   = (int*)alloc(256 * 4);
    int*   col    = (int*)alloc((size_t)N_EDGES * 4);
    float* s12    = (float*)alloc(DEPTH * 256 * 4);
    int*   moloff = (int*)alloc((N_MOLS + 1) * 4);

    const __half* Wt_in = Wt;
    const __half* W1t   = Wt + 128 * K_IN_PAD;
    const __half* W2t   = W1t + DEPTH * 128 * 128;

    // ---- CSR build ----
    hipMemsetAsync(wcur, 0, N_ATOMS * 4, stream);
    hist_kernel<<<(N_EDGES + 255) / 256, 256, 0, stream>>>(tgt, N_EDGES, wcur);
    const int NB = (N_ATOMS + 255) / 256;
    scan_block_kernel<<<NB, 256, 0, stream>>>(wcur, partial, bsum, N_ATOMS);
    scan_top_kernel<<<1, 256, 0, stream>>>(bsum, NB);
    scan_add_kernel<<<NB, 256, 0, stream>>>(partial, bsum, rowptr, wcur, N_ATOMS, N_EDGES);
    fill_csr_kernel<<<(N_EDGES + 255) / 256, 256, 0, stream>>>(src, tgt, N_EDGES, wcur, col);

    // ---- mol offsets + zero stats; input/weight conversion ----
    mol_offsets_zero_kernel<<<5, 256, 0, stream>>>(seg, moloff, s12);
    convert_atoms_kernel<<<(N_ATOMS * (K_IN_PAD / 4) + 255) / 256, 256, 0, stream>>>(f_atoms, Ah);
    convert_weights_kernel<<<(128 * K_IN_PAD + 2 * DEPTH * 128 * 128 + 255) / 256, 256, 0, stream>>>(
        W_in, W1, W2, Wt);

    // ---- input projection + ReLU -> fp16 x ----
    const int GB = (N_ATOMS + 127) / 128;   // 391
    mfma_gemm<true, false><<<GB, 256, 0, stream>>>(
        Ah, Wt_in, b_in, xh, N_ATOMS, K_IN_PAD, nullptr, nullptr);

    for (int d = 0; d < DEPTH; ++d) {
        float* s1d = s12 + d * 256;
        float* s2d = s1d + 128;
        aggregate_kernel<<<N_ATOMS / 4, 256, 0, stream>>>(
            (const __half2*)xh, rowptr, col, eps_param, d, (__half2*)aggh);
        mfma_gemm<true, false><<<GB, 256, 0, stream>>>(
            aggh, W1t + (size_t)d * 128 * 128, b1 + d * HIDDEN, hh,
            N_ATOMS, HIDDEN, nullptr, nullptr);
        mfma_gemm<false, true><<<GB, 256, 0, stream>>>(
            hh, W2t + (size_t)d * 128 * 128, b2 + d * HIDDEN, aggh,
            N_ATOMS, HIDDEN, s1d, s2d);
        bn_apply_relu_kernel<<<(N_ATOMS * 128 / 4 + 255) / 256, 256, 0, stream>>>(
            aggh, s1d, s2d, gamma, beta, d, xh);
    }

    pool_kernel<<<N_MOLS, 128, 0, stream>>>(xh, moloff, out);
}

// Round 4
// 434.729 us; speedup vs baseline: 1.9907x; 1.1258x over previous
//
#include <hip/hip_runtime.h>
#include <hip/hip_fp16.h>

#define N_ATOMS   50000
#define ATOM_FDIM 133
#define HIDDEN    128
#define DEPTH     3
#define N_EDGES   800000
#define N_MOLS    1024
#define BN_EPS    1e-5f
#define K_IN_PAD  160   // 133 padded to 5*32

typedef _Float16 f16x8 __attribute__((ext_vector_type(8)));
typedef float    f32x4 __attribute__((ext_vector_type(4)));

struct __align__(8) half4pack { __half2 a, b; };

// ---------------- histogram ----------------
__global__ void hist_kernel(const int* __restrict__ idx, int n, int* __restrict__ cnt) {
    int i = blockIdx.x * blockDim.x + threadIdx.x;
    if (i < n) atomicAdd(&cnt[idx[i]], 1);
}

// ---------------- hierarchical exclusive scan ----------------
__global__ void scan_block_kernel(const int* __restrict__ in, int* __restrict__ out,
                                  int* __restrict__ bsum, int n) {
    __shared__ int buf[256];
    int i = blockIdx.x * 256 + threadIdx.x;
    int v = (i < n) ? in[i] : 0;
    buf[threadIdx.x] = v;
    __syncthreads();
    #pragma unroll
    for (int off = 1; off < 256; off <<= 1) {
        int t = (threadIdx.x >= off) ? buf[threadIdx.x - off] : 0;
        __syncthreads();
        buf[threadIdx.x] += t;
        __syncthreads();
    }
    if (i < n) out[i] = buf[threadIdx.x] - v;
    if (threadIdx.x == 255) bsum[blockIdx.x] = buf[255];
}

__global__ void scan_top_kernel(int* __restrict__ bsum, int nb) {
    __shared__ int buf[256];
    int v = (threadIdx.x < nb) ? bsum[threadIdx.x] : 0;
    buf[threadIdx.x] = v;
    __syncthreads();
    #pragma unroll
    for (int off = 1; off < 256; off <<= 1) {
        int t = (threadIdx.x >= off) ? buf[threadIdx.x - off] : 0;
        __syncthreads();
        buf[threadIdx.x] += t;
        __syncthreads();
    }
    if (threadIdx.x < nb) bsum[threadIdx.x] = buf[threadIdx.x] - v;
}

__global__ void scan_add_kernel(const int* __restrict__ partial, const int* __restrict__ bsum,
                                int* __restrict__ rowptr, int* __restrict__ wcur,
                                int n, int total) {
    int i = blockIdx.x * 256 + threadIdx.x;
    if (i < n) {
        int v = partial[i] + bsum[blockIdx.x];
        rowptr[i] = v;
        wcur[i]   = v;
    }
    if (i == 0) rowptr[n] = total;
}

// ---------------- CSR fill (col as uint16: src < 65536) ----------------
__global__ void fill_csr_kernel(const int* __restrict__ src, const int* __restrict__ tgt,
                                int n, int* __restrict__ wcur, unsigned short* __restrict__ col) {
    int e = blockIdx.x * blockDim.x + threadIdx.x;
    if (e < n) {
        int t = tgt[e];
        int p = atomicAdd(&wcur[t], 1);
        col[p] = (unsigned short)src[e];
    }
}

// ---------------- fused setup: atoms->fp16(pad), weights->fp16^T, stats zero, mol offsets ----
__global__ void setup_kernel(const float* __restrict__ f,
                             const float* __restrict__ W_in,
                             const float* __restrict__ W1,
                             const float* __restrict__ W2,
                             const int* __restrict__ seg,
                             __half* __restrict__ Ah, __half* __restrict__ Wt,
                             float* __restrict__ stats, int* __restrict__ moloff)
{
    const int NCH = N_ATOMS * (K_IN_PAD / 4);                    // 2,000,000 half4 chunks
    const int NW4 = (128 * K_IN_PAD + 2 * DEPTH * 128 * 128) / 4; // 29,696 half4 chunks
    int i = blockIdx.x * 256 + threadIdx.x;
    if (i < NCH) {
        int row = i / (K_IN_PAD / 4);
        int c4  = (i - row * (K_IN_PAD / 4)) * 4;
        float v[4];
        #pragma unroll
        for (int u = 0; u < 4; ++u) {
            int k = c4 + u;
            v[u] = (k < ATOM_FDIM) ? f[(size_t)row * ATOM_FDIM + k] : 0.f;
        }
        half4pack p;
        p.a = __float22half2_rn(make_float2(v[0], v[1]));
        p.b = __float22half2_rn(make_float2(v[2], v[3]));
        *(half4pack*)&Ah[(size_t)row * K_IN_PAD + c4] = p;
        return;
    }
    int j = i - NCH;
    if (j < NW4) {
        float v[4];
        #pragma unroll
        for (int u = 0; u < 4; ++u) {
            int e = j * 4 + u;
            if (e < 128 * K_IN_PAD) {
                int n = e / K_IN_PAD, k = e - n * K_IN_PAD;
                v[u] = (k < ATOM_FDIM) ? W_in[(size_t)k * 128 + n] : 0.f;
            } else if (e < 128 * K_IN_PAD + DEPTH * 128 * 128) {
                int q = e - 128 * K_IN_PAD;
                int d = q >> 14, r = q & 16383;
                int n = r >> 7, k = r & 127;
                v[u] = W1[((size_t)d * 128 + k) * 128 + n];
            } else {
                int q = e - 128 * K_IN_PAD - DEPTH * 128 * 128;
                int d = q >> 14, r = q & 16383;
                int n = r >> 7, k = r & 127;
                v[u] = W2[((size_t)d * 128 + k) * 128 + n];
            }
        }
        half4pack p;
        p.a = __float22half2_rn(make_float2(v[0], v[1]));
        p.b = __float22half2_rn(make_float2(v[2], v[3]));
        *(half4pack*)&Wt[j * 4] = p;
        return;
    }
    int m = j - NW4;
    if (m < DEPTH * 256) stats[m] = 0.f;
    if (m <= N_MOLS) {
        int lo = 0, hi = N_ATOMS;
        while (lo < hi) {
            int mid = (lo + hi) >> 1;
            if (seg[mid] < m) lo = mid + 1; else hi = mid;
        }
        moloff[m] = lo;
    }
}

#define LDS_S 40   // padded stride (halves) per 32-half k-chunk row

// ---------------- MFMA GEMM, K variable (input projection) ----------------
template<bool RELU, bool STATS>
__global__ __launch_bounds__(256, 2) void mfma_gemm(
    const __half* __restrict__ A, const __half* __restrict__ Bt,
    const float* __restrict__ bias, __half* __restrict__ C,
    int M, int K, float* __restrict__ s1, float* __restrict__ s2)
{
    __shared__ __align__(16) __half As[128 * LDS_S];
    __shared__ __align__(16) __half Bs[128 * LDS_S];

    const int t = threadIdx.x;
    const int w = t >> 6, lane = t & 63;
    const int wm = w >> 1, wn = w & 1;
    const int l15 = lane & 15, quad = lane >> 4;
    const int row0 = blockIdx.x * 128;

    f32x4 acc[4][4];
    #pragma unroll
    for (int mt = 0; mt < 4; ++mt)
        #pragma unroll
        for (int nt = 0; nt < 4; ++nt) acc[mt][nt] = (f32x4){0.f, 0.f, 0.f, 0.f};

    for (int k0 = 0; k0 < K; k0 += 32) {
        #pragma unroll
        for (int i = 0; i < 2; ++i) {
            int c = t * 2 + i;
            int r = c >> 2, o = c & 3;
            int row = row0 + r;
            uint4 v = make_uint4(0, 0, 0, 0);
            if (row < M) v = *(const uint4*)&A[(size_t)row * K + k0 + o * 8];
            *(uint4*)&As[r * LDS_S + o * 8] = v;
        }
        #pragma unroll
        for (int i = 0; i < 2; ++i) {
            int c = t * 2 + i;
            int r = c >> 2, o = c & 3;
            uint4 v = *(const uint4*)&Bt[(size_t)r * K + k0 + o * 8];
            *(uint4*)&Bs[r * LDS_S + o * 8] = v;
        }
        __syncthreads();
        f16x8 af[4], bf[4];
        #pragma unroll
        for (int mt = 0; mt < 4; ++mt)
            af[mt] = *(const f16x8*)&As[(wm * 64 + mt * 16 + l15) * LDS_S + quad * 8];
        #pragma unroll
        for (int nt = 0; nt < 4; ++nt)
            bf[nt] = *(const f16x8*)&Bs[(wn * 64 + nt * 16 + l15) * LDS_S + quad * 8];
        #pragma unroll
        for (int mt = 0; mt < 4; ++mt)
            #pragma unroll
            for (int nt = 0; nt < 4; ++nt)
                acc[mt][nt] = __builtin_amdgcn_mfma_f32_16x16x32_f16(af[mt], bf[nt], acc[mt][nt], 0, 0, 0);
        __syncthreads();
    }

    #pragma unroll
    for (int nt = 0; nt < 4; ++nt) {
        int col = wn * 64 + nt * 16 + l15;
        float b = bias[col];
        #pragma unroll
        for (int mt = 0; mt < 4; ++mt) {
            #pragma unroll
            for (int r = 0; r < 4; ++r) {
                int row = row0 + wm * 64 + mt * 16 + quad * 4 + r;
                if (row < M) {
                    float o = acc[mt][nt][r] + b;
                    if (RELU) o = fmaxf(o, 0.f);
                    C[(size_t)row * 128 + col] = __float2half(o);
                }
            }
        }
    }
}

// ---------------- MFMA GEMM, K=128 fixed: whole tile staged, ONE barrier ----------------
template<bool RELU, bool STATS>
__global__ __launch_bounds__(256, 2) void mfma_gemm128(
    const __half* __restrict__ A, const __half* __restrict__ Bt,
    const float* __restrict__ bias, __half* __restrict__ C,
    int M, float* __restrict__ s1, float* __restrict__ s2)
{
    __shared__ __align__(16) __half As[4 * 128 * LDS_S];  // 40 KB: [kc][r][o*8]
    __shared__ __align__(16) __half Bs[4 * 128 * LDS_S];  // 40 KB

    const int t = threadIdx.x;
    const int w = t >> 6, lane = t & 63;
    const int wm = w >> 1, wn = w & 1;
    const int l15 = lane & 15, quad = lane >> 4;
    const int row0 = blockIdx.x * 128;

    f32x4 acc[4][4];
    #pragma unroll
    for (int mt = 0; mt < 4; ++mt)
        #pragma unroll
        for (int nt = 0; nt < 4; ++nt) acc[mt][nt] = (f32x4){0.f, 0.f, 0.f, 0.f};

    // stage A: 128 rows x 256 B = 2048 16B-chunks; 8 per thread, coalesced
    #pragma unroll
    for (int i = 0; i < 8; ++i) {
        int c = i * 256 + t;
        int r = c >> 4, o = c & 15;
        int kc = o >> 2, oo = o & 3;
        int row = row0 + r;
        uint4 v = make_uint4(0, 0, 0, 0);
        if (row < M) v = *(const uint4*)&A[(size_t)row * 128 + o * 8];
        *(uint4*)&As[(kc * 128 + r) * LDS_S + oo * 8] = v;
    }
    // stage B (whole 128x128 weight)
    #pragma unroll
    for (int i = 0; i < 8; ++i) {
        int c = i * 256 + t;
        int r = c >> 4, o = c & 15;
        int kc = o >> 2, oo = o & 3;
        uint4 v = *(const uint4*)&Bt[(size_t)r * 128 + o * 8];
        *(uint4*)&Bs[(kc * 128 + r) * LDS_S + oo * 8] = v;
    }
    __syncthreads();

    #pragma unroll
    for (int kc = 0; kc < 4; ++kc) {
        f16x8 af[4], bf[4];
        #pragma unroll
        for (int mt = 0; mt < 4; ++mt)
            af[mt] = *(const f16x8*)&As[(kc * 128 + wm * 64 + mt * 16 + l15) * LDS_S + quad * 8];
        #pragma unroll
        for (int nt = 0; nt < 4; ++nt)
            bf[nt] = *(const f16x8*)&Bs[(kc * 128 + wn * 64 + nt * 16 + l15) * LDS_S + quad * 8];
        #pragma unroll
        for (int mt = 0; mt < 4; ++mt)
            #pragma unroll
            for (int nt = 0; nt < 4; ++nt)
                acc[mt][nt] = __builtin_amdgcn_mfma_f32_16x16x32_f16(af[mt], bf[nt], acc[mt][nt], 0, 0, 0);
    }

    // epilogue: C/D layout col = lane&15, row = quad*4 + reg
    float ps[4] = {0, 0, 0, 0}, pss[4] = {0, 0, 0, 0};
    #pragma unroll
    for (int nt = 0; nt < 4; ++nt) {
        int col = wn * 64 + nt * 16 + l15;
        float b = bias[col];
        #pragma unroll
        for (int mt = 0; mt < 4; ++mt) {
            #pragma unroll
            for (int r = 0; r < 4; ++r) {
                int row = row0 + wm * 64 + mt * 16 + quad * 4 + r;
                if (row < M) {
                    float o = acc[mt][nt][r] + b;
                    if (STATS) { ps[nt] += o; pss[nt] += o * o; }
                    if (RELU) o = fmaxf(o, 0.f);
                    C[(size_t)row * 128 + col] = __float2half(o);
                }
            }
        }
    }

    if (STATS) {
        float* red1 = (float*)As;   // 8*128 floats = 4 KB
        float* red2 = (float*)Bs;
        int contrib = wm * 4 + quad;          // 0..7
        __syncthreads();
        #pragma unroll
        for (int nt = 0; nt < 4; ++nt) {
            int col = wn * 64 + nt * 16 + l15;
            red1[contrib * 128 + col] = ps[nt];
            red2[contrib * 128 + col] = pss[nt];
        }
        __syncthreads();
        if (t < 128) {
            float s = 0.f, q = 0.f;
            #pragma unroll
            for (int g = 0; g < 8; ++g) {
                s += red1[g * 128 + t];
                q += red2[g * 128 + t];
            }
            atomicAdd(&s1[t], s);
            atomicAdd(&s2[t], q);
        }
    }
}

// ---------------- aggregate, optional fused BN+ReLU on gathered source ----------------
// BN=false: src = x (already activated).  BN=true: src = pre-BN h; apply per-element
// x = max(h*sc+sh, 0) with sc/sh from depth-(dprev) batch stats.
template<bool BN>
__global__ __launch_bounds__(256) void aggregate_kernel(
    const __half2* __restrict__ xh2, const int* __restrict__ rowptr,
    const unsigned short* __restrict__ col, const float* __restrict__ eps_param, int d,
    const float* __restrict__ s1, const float* __restrict__ s2,
    const float* __restrict__ gamma, const float* __restrict__ beta, int dprev,
    __half2* __restrict__ aggh2)
{
    int gw = (blockIdx.x * 256 + threadIdx.x) >> 6;   // one wave per atom
    int lane = threadIdx.x & 63;
    float e1 = 1.0f + eps_param[d];

    float2 sc = make_float2(0.f, 0.f), sh = make_float2(0.f, 0.f);
    if (BN) {
        const float inv_n = 1.0f / (float)N_ATOMS;
        int c0 = lane * 2;
        float m0 = s1[c0] * inv_n;
        float v0 = fmaxf(s2[c0] * inv_n - m0 * m0, 0.f);
        float m1 = s1[c0 + 1] * inv_n;
        float v1 = fmaxf(s2[c0 + 1] * inv_n - m1 * m1, 0.f);
        sc.x = gamma[dprev * 128 + c0]     * rsqrtf(v0 + BN_EPS);
        sc.y = gamma[dprev * 128 + c0 + 1] * rsqrtf(v1 + BN_EPS);
        sh.x = beta[dprev * 128 + c0]     - m0 * sc.x;
        sh.y = beta[dprev * 128 + c0 + 1] - m1 * sc.y;
    }

    float2 a = __half22float2(xh2[(size_t)gw * 64 + lane]);
    if (BN) {
        a.x = fmaxf(a.x * sc.x + sh.x, 0.f);
        a.y = fmaxf(a.y * sc.y + sh.y, 0.f);
    }
    float2 acc;
    acc.x = a.x * e1;
    acc.y = a.y * e1;

    int s = rowptr[gw], e = rowptr[gw + 1];
    for (int i = s; i < e; i += 8) {
        #pragma unroll
        for (int u = 0; u < 8; ++u) {
            int idx = i + u;
            int c = col[min(idx, e - 1)];
            float2 f = __half22float2(xh2[(size_t)c * 64 + lane]);
            if (BN) {
                f.x = fmaxf(f.x * sc.x + sh.x, 0.f);
                f.y = fmaxf(f.y * sc.y + sh.y, 0.f);
            }
            if (idx < e) {
                acc.x += f.x;
                acc.y += f.y;
            }
        }
    }
    aggh2[(size_t)gw * 64 + lane] = __float22half2_rn(acc);
}

// ---------------- per-molecule mean pooling with fused BN+ReLU ----------------
__global__ void pool_kernel(const __half* __restrict__ hh, const int* __restrict__ off,
                            const float* __restrict__ s1, const float* __restrict__ s2,
                            const float* __restrict__ gamma, const float* __restrict__ beta,
                            int dprev, float* __restrict__ out)
{
    int m = blockIdx.x;
    int c = threadIdx.x;     // 128 threads
    const float inv_n = 1.0f / (float)N_ATOMS;
    float mean = s1[c] * inv_n;
    float var = fmaxf(s2[c] * inv_n - mean * mean, 0.f);
    float sc = gamma[dprev * 128 + c] * rsqrtf(var + BN_EPS);
    float sh = beta[dprev * 128 + c] - mean * sc;
    int s = off[m], e = off[m + 1];
    float acc = 0.f;
    for (int r = s; r < e; ++r) {
        float v = __half2float(hh[(size_t)r * 128 + c]);
        acc += fmaxf(v * sc + sh, 0.f);
    }
    int cnt = e - s;
    out[m * 128 + c] = (cnt > 0) ? acc / (float)cnt : 0.f;
}

// ---------------- launcher ----------------
extern "C" void kernel_launch(void* const* d_in, const int* in_sizes, int n_in,
                              void* d_out, int out_size, void* d_ws, size_t ws_size,
                              hipStream_t stream)
{
    const float* f_atoms   = (const float*)d_in[0];
    const float* W_in      = (const float*)d_in[1];
    const float* b_in      = (const float*)d_in[2];
    const float* W1        = (const float*)d_in[3];
    const float* b1        = (const float*)d_in[4];
    const float* W2        = (const float*)d_in[5];
    const float* b2        = (const float*)d_in[6];
    const float* gamma     = (const float*)d_in[7];
    const float* beta      = (const float*)d_in[8];
    const float* eps_param = (const float*)d_in[9];
    const int*   edge_index= (const int*)d_in[10];
    const int*   seg       = (const int*)d_in[11];
    const int*   src = edge_index;
    const int*   tgt = edge_index + N_EDGES;
    float* out = (float*)d_out;

    char* ws = (char*)d_ws;
    size_t off = 0;
    auto alloc = [&](size_t bytes) -> char* {
        char* p = ws + off;
        off += (bytes + 255) & ~(size_t)255;
        return p;
    };
    __half* xh    = (__half*)alloc((size_t)N_ATOMS * HIDDEN * 2);   // x0 = relu(proj)
    __half* aggh  = (__half*)alloc((size_t)N_ATOMS * HIDDEN * 2);   // aggregate out / GEMM A
    __half* hh    = (__half*)alloc((size_t)N_ATOMS * HIDDEN * 2);   // gemm1 out
    __half* hpre  = (__half*)alloc((size_t)N_ATOMS * HIDDEN * 2);   // gemm2 out (pre-BN h)
    __half* Ah    = (__half*)alloc((size_t)N_ATOMS * K_IN_PAD * 2);
    __half* Wt    = (__half*)alloc((size_t)(128 * K_IN_PAD + 2 * DEPTH * 128 * 128) * 2);
    int*   rowptr = (int*)alloc((N_ATOMS + 1) * 4);
    int*   wcur   = (int*)alloc(N_ATOMS * 4);
    int*   partial= (int*)alloc(N_ATOMS * 4);
    int*   bsum   = (int*)alloc(256 * 4);
    unsigned short* col = (unsigned short*)alloc((size_t)N_EDGES * 2);
    float* s12    = (float*)alloc(DEPTH * 256 * 4);
    int*   moloff = (int*)alloc((N_MOLS + 1) * 4);

    const __half* Wt_in = Wt;
    const __half* W1t   = Wt + 128 * K_IN_PAD;
    const __half* W2t   = W1t + DEPTH * 128 * 128;

    // ---- CSR build ----
    hipMemsetAsync(wcur, 0, N_ATOMS * 4, stream);
    hist_kernel<<<(N_EDGES + 255) / 256, 256, 0, stream>>>(tgt, N_EDGES, wcur);
    const int NB = (N_ATOMS + 255) / 256;
    scan_block_kernel<<<NB, 256, 0, stream>>>(wcur, partial, bsum, N_ATOMS);
    scan_top_kernel<<<1, 256, 0, stream>>>(bsum, NB);
    scan_add_kernel<<<NB, 256, 0, stream>>>(partial, bsum, rowptr, wcur, N_ATOMS, N_EDGES);
    fill_csr_kernel<<<(N_EDGES + 255) / 256, 256, 0, stream>>>(src, tgt, N_EDGES, wcur, col);

    // ---- fused setup (atoms fp16, weights fp16^T, stats zero, mol offsets) ----
    {
        const int NCH = N_ATOMS * (K_IN_PAD / 4);
        const int NW4 = (128 * K_IN_PAD + 2 * DEPTH * 128 * 128) / 4;
        const int TOT = NCH + NW4 + N_MOLS + 1;
        setup_kernel<<<(TOT + 255) / 256, 256, 0, stream>>>(
            f_atoms, W_in, W1, W2, seg, Ah, Wt, s12, moloff);
    }

    // ---- input projection + ReLU -> fp16 x0 ----
    const int GB = (N_ATOMS + 127) / 128;   // 391
    mfma_gemm<true, false><<<GB, 256, 0, stream>>>(
        Ah, Wt_in, b_in, xh, N_ATOMS, K_IN_PAD, nullptr, nullptr);

    for (int d = 0; d < DEPTH; ++d) {
        float* s1d = s12 + d * 256;
        float* s2d = s1d + 128;
        if (d == 0) {
            aggregate_kernel<false><<<N_ATOMS / 4, 256, 0, stream>>>(
                (const __half2*)xh, rowptr, col, eps_param, d,
                nullptr, nullptr, nullptr, nullptr, 0, (__half2*)aggh);
        } else {
            float* s1p = s12 + (d - 1) * 256;
            float* s2p = s1p + 128;
            aggregate_kernel<true><<<N_ATOMS / 4, 256, 0, stream>>>(
                (const __half2*)hpre, rowptr, col, eps_param, d,
                s1p, s2p, gamma, beta, d - 1, (__half2*)aggh);
        }
        mfma_gemm128<true, false><<<GB, 256, 0, stream>>>(
            aggh, W1t + (size_t)d * 128 * 128, b1 + d * HIDDEN, hh,
            N_ATOMS, nullptr, nullptr);
        mfma_gemm128<false, true><<<GB, 256, 0, stream>>>(
            hh, W2t + (size_t)d * 128 * 128, b2 + d * HIDDEN, hpre,
            N_ATOMS, s1d, s2d);
    }

    pool_kernel<<<N_MOLS, 128, 0, stream>>>(
        hpre, moloff, s12 + (DEPTH - 1) * 256, s12 + (DEPTH - 1) * 256 + 128,
        gamma, beta, DEPTH - 1, out);
}